// Round 15
// baseline (208.685 us; speedup 1.0000x reference)
//
#include <hip/hip_runtime.h>

typedef _Float16 f16;
typedef f16 f16x4 __attribute__((ext_vector_type(4)));
typedef f16 f16x8 __attribute__((ext_vector_type(8)));
typedef float f32x4 __attribute__((ext_vector_type(4)));

#define RES 512
#define PTS 128     // mlp: points per block
#define XS  136     // f16 stride: 272B row, 16B-aligned, b128 phase-minimal
#define AS  20      // 40B row: aug xb4 banks (10*l15)%32 all-distinct -> conflict-free

// R25: three deltas on R24 (206.5us; mlp 66.0, sample ~62-66):
//  (1) mlp AS 16->20: R24's K=16 aug xb4 read at 32B rows was a 4-way bank
//      conflict I introduced (banks (8*l15)%32 = {0,8,16,24}; counter jumped
//      4.2M->6.2M = ~10us LDS time). 40B rows -> (10*l15)%32 = 16 distinct.
//      LDS 78336B, still 2 blocks/CU.
//  (2) sample ILP 4->8 (8 pts/thread, grid 1024): R18 proved the
//      outstanding-slot mechanism; double in-flight again. VGPR ~90 < 128.
//  (3) 64B-tile texel layout: line covers 4x8 texels (vs 2x16) ->
//      E[lines/sample] 1.55->1.41. quad_tap unchanged; quad index = ry+cx
//      (ry=(qy>>1)*512+(qy&1)*4, cx=(qx>>2)*8+(qx&3)). pack_all quad branch
//      -> 1024-block tile packer, coalesced both sides.

// ---------------------------------------------------------------- pack kernels
__device__ __forceinline__
void pack_w_body(int g, const float* __restrict__ lw, const float* __restrict__ lnw,
                 const float* __restrict__ lb, const float* __restrict__ tw1,
                 const float* __restrict__ tb1, const float* __restrict__ ivec,
                 f16* __restrict__ wf, f16* __restrict__ waugf) {
    if (g < 10240) {            // Wm fragments: 5 layers x 32 frags x 64 lanes
        const int L = g >> 11, r = g & 2047;
        const int lane = r & 63, frag = r >> 6;
        const int q = lane >> 4, l15 = lane & 15;
        const int mt = frag >> 2, c = frag & 3;
        const float* src = ((L < 4) ? (lw + L * 16384) : tw1)
                           + (mt * 16 + l15) * 128 + c * 32 + q * 8;
        f16x8 h;
        #pragma unroll
        for (int j = 0; j < 8; ++j) h[j] = (f16)src[j];
        *(f16x8*)(wf + (size_t)g * 8) = h;
    } else {                    // Waug K=16 frags: 5 layers x 8 frags x 64 lanes
        const int ga = g - 10240;            // < 2560
        const int L = ga >> 9, r = ga & 511;
        const int lane = r & 63, mt = r >> 6;
        const int q = lane >> 4, l15 = lane & 15;
        const int row = mt * 16 + l15;
        f16x4 h = {};
        if (L < 4 && q < 2) {                // k=q*4+j in 0..7: lnw slice
            const float* src = lnw + L * 1024 + row * 8 + q * 4;
            #pragma unroll
            for (int j = 0; j < 4; ++j) h[j] = (f16)src[j];
        }
        if (q == 2) {                        // k=8: bias (L0: + lw0@ivec const)
            if (L == 0) {
                float s = lb[row];
                const float4* w4 = (const float4*)(lw + row * 128);
                const float4* v4 = (const float4*)ivec;
                #pragma unroll 8
                for (int k = 0; k < 32; ++k) {
                    const float4 w = w4[k], v = v4[k];
                    s += w.x * v.x + w.y * v.y + w.z * v.z + w.w * v.w;
                }
                h[0] = (f16)s;
            } else {
                h[0] = (f16)((L < 4) ? lb[L * 128 + row] : tb1[row]);
            }
        }
        *(f16x4*)(waugf + (size_t)ga * 4) = h;
    }
}

__global__ __launch_bounds__(256)
void pack_all_k(const float* __restrict__ n, f16* __restrict__ q,
                const float* __restrict__ lw,  const float* __restrict__ lnw,
                const float* __restrict__ lb,  const float* __restrict__ tw1,
                const float* __restrict__ tb1, const float* __restrict__ ivec,
                f16* __restrict__ wf, f16* __restrict__ waugf) {
    const int b = blockIdx.x;
    if (b < 1024) {   // tile64 packing: one thread per 4x8-texel tile (64B)
        const int idx = b * 256 + threadIdx.x;       // m*8192 + ty*64 + tx
        const int tx = idx & 63, rest = idx >> 6;
        const int ty = rest & 127, m = rest >> 7;
        const float* src = n + ((size_t)m * 512 + 4 * ty) * 512 + 8 * tx;
        f16 row[4][8];
        #pragma unroll
        for (int r = 0; r < 4; ++r) {
            const float4 a = *(const float4*)(src + r * 512);
            const float4 c = *(const float4*)(src + r * 512 + 4);
            row[r][0]=(f16)a.x; row[r][1]=(f16)a.y; row[r][2]=(f16)a.z; row[r][3]=(f16)a.w;
            row[r][4]=(f16)c.x; row[r][5]=(f16)c.y; row[r][6]=(f16)c.z; row[r][7]=(f16)c.w;
        }
        f16* dst = q + (size_t)idx * 32;             // 8 quads x 4 f16 = 64B
        #pragma unroll
        for (int qr = 0; qr < 2; ++qr)
            #pragma unroll
            for (int qc = 0; qc < 4; ++qc) {
                f16x4 o;
                o[0] = row[2*qr][2*qc];   o[1] = row[2*qr][2*qc+1];
                o[2] = row[2*qr+1][2*qc]; o[3] = row[2*qr+1][2*qc+1];
                *(f16x4*)(dst + (qr * 4 + qc) * 4) = o;
            }
    } else {
        pack_w_body((b - 1024) * 256 + threadIdx.x, lw, lnw, lb, tw1, tb1, ivec, wf, waugf);
    }
}

__global__ __launch_bounds__(256)
void pack_w_k(const float* __restrict__ lw,  const float* __restrict__ lnw,
              const float* __restrict__ lb,  const float* __restrict__ tw1,
              const float* __restrict__ tb1, const float* __restrict__ ivec,
              f16* __restrict__ wf, f16* __restrict__ waugf) {
    pack_w_body(blockIdx.x * 256 + threadIdx.x, lw, lnw, lb, tw1, tb1, ivec, wf, waugf);
}

// ---------------------------------------------------------------- sample kernel
__device__ __forceinline__ float quad_tap(uint2 q, int sy, int sx) {
    unsigned w = sy ? q.y : q.x;          // row select within quad
    w >>= (sx << 4);                      // col select (low/high half)
    union { unsigned short u; f16 h; } cv; cv.u = (unsigned short)w;
    return (float)cv.h;
}

template <bool QUAD>
__global__ __launch_bounds__(256, 4)
void sample_kernel(const void* __restrict__ noise_v,
                   const float* __restrict__ coords,
                   const float* __restrict__ trans,
                   f16* __restrict__ nv_ws, const int Ntot)
{
    __shared__ float T_sh[128];
    const int t = threadIdx.x;
    if (t < 128) T_sh[t] = trans[t];
    __syncthreads();

    const int g = blockIdx.x & 7;                     // feature group -> XCD pin
    const int pb = (blockIdx.x >> 3) * 2048 + t;      // 8 points: pb + 256*j

    // cost-balanced plane sets (expensive planes m=9..31 split 3/..3/2)
    int mk[4];
    if (g < 7) { mk[0] = g; mk[1] = g + 9; mk[2] = g + 17; mk[3] = g + 25; }
    else       { mk[0] = 7; mk[1] = 8;     mk[2] = 16;     mk[3] = 24;     }

    float2 c[8];
    #pragma unroll
    for (int j = 0; j < 8; ++j)
        c[j] = *(const float2*)(coords + (pb + 256 * j) * 2);

    float nvr[8][4];
    {
        #pragma clang fp contract(off)
        #pragma unroll
        for (int j = 0; j < 8; ++j) {
            const float cx = c[j].x;
            const float cy = c[j].y;
            #pragma unroll
            for (int k = 0; k < 4; ++k) {
                const int m = mk[k];
                const float T00 = T_sh[m*4+0], T01 = T_sh[m*4+1];
                const float T10 = T_sh[m*4+2], T11 = T_sh[m*4+3];
                const float p0x = T00 * cx;                       // k=0: fl(cx*T00)
                const float p0y = T10 * cx;
                const float ncx = __builtin_fmaf(T01, cy, p0x);   // k=1: fused accumulate
                const float ncy = __builtin_fmaf(T11, cy, p0y);
                const float u = ncx - 0.5f;
                const float v = ncy - 0.5f;
                const float xf = floorf(u), yf = floorf(v);
                const float xw = u - xf, yw = v - yf;
                int ix = (xf >= 2147483648.0f || xf < -2147483648.0f) ? (int)(-2147483647 - 1) : (int)xf;
                int iy = (yf >= 2147483648.0f || yf < -2147483648.0f) ? (int)(-2147483647 - 1) : (int)yf;
                const int x0 = ix & (RES - 1);
                const int x1 = (int)(((unsigned)ix + 1u) & (unsigned)(RES - 1));
                const int y0 = iy & (RES - 1);
                const int y1 = (int)(((unsigned)iy + 1u) & (unsigned)(RES - 1));
                float i00, i01, i10, i11;
                if constexpr (QUAD) {
                    const f16* pl = (const f16*)noise_v + (size_t)m * (256 * 256 * 4);
                    const int qx0 = x0 >> 1, sx0 = x0 & 1;
                    const int qx1 = x1 >> 1, sx1 = x1 & 1;
                    const int qy0 = y0 >> 1, sy0 = y0 & 1;
                    const int qy1 = y1 >> 1, sy1 = y1 & 1;
                    // tile64 layout: quad index = ry + cx
                    const int ry0 = (qy0 >> 1) * 512 + (qy0 & 1) * 4;
                    const int ry1 = (qy1 >> 1) * 512 + (qy1 & 1) * 4;
                    const int cx0 = (qx0 >> 2) * 8 + (qx0 & 3);
                    const int cx1 = (qx1 >> 2) * 8 + (qx1 & 3);
                    const uint2 qa = *(const uint2*)(pl + (ry0 + cx0) * 4);
                    const uint2 qb = *(const uint2*)(pl + (ry0 + cx1) * 4);
                    const uint2 qc = *(const uint2*)(pl + (ry1 + cx0) * 4);
                    const uint2 qd = *(const uint2*)(pl + (ry1 + cx1) * 4);
                    i00 = quad_tap(qa, sy0, sx0);
                    i01 = quad_tap(qb, sy0, sx1);
                    i10 = quad_tap(qc, sy1, sx0);
                    i11 = quad_tap(qd, sy1, sx1);
                } else {
                    const float* pl = (const float*)noise_v + (size_t)m * (RES * RES);
                    i00 = pl[y0 * RES + x0];
                    i01 = pl[y0 * RES + x1];
                    i10 = pl[y1 * RES + x0];
                    i11 = pl[y1 * RES + x1];
                }
                const float a0 = i00 + (i01 - i00) * xw;
                const float a1 = i10 + (i11 - i10) * xw;
                nvr[j][k] = a0 + (a1 - a0) * yw;
            }
        }
    }
    #pragma unroll
    for (int j = 0; j < 8; ++j) {
        #pragma unroll
        for (int k = 0; k < 4; ++k) {          // nv slot(m) = (m&7)*4 + (m>>3)
            const int m = mk[k];
            const int slot = (m & 7) * 4 + (m >> 3);
            nv_ws[(size_t)slot * Ntot + pb + 256 * j] = (f16)nvr[j][k];
        }
    }
}

// ---------------------------------------------------------------- mlp kernel
__global__ __launch_bounds__(256, 2)
void mlp_kernel(const f16* __restrict__ nv_ws,
                const f16* __restrict__ wf,
                const f16* __restrict__ waugf,
                const float* __restrict__ tw2,
                const float* __restrict__ tb2,
                float* __restrict__ out, const int Ntot)
{
    __shared__ f16 Wm[16384];           // 32 frags x 512 f16 = 32768 B, lane-linear
    __shared__ f16 Waug[2048];          //  8 K16-frags x 256 f16 = 4096 B
    __shared__ f16 xa[PTS * XS];        // 34816 B
    __shared__ f16 xaug[PTS * AS];      //  5120 B (40B rows, conflict-free xb4)
    __shared__ __align__(16) float tw2_sh[128];   // 512 B
    __shared__ float pp[2][PTS];        // 1024 B; total 78336 B

    const int t    = threadIdx.x;
    const int wave = t >> 6;
    const int lane = t & 63;
    const int q    = lane >> 4;
    const int l15  = lane & 15;
    const int wi   = wave >> 1;         // point-half  [wi*64, +64)
    const int wj   = wave & 1;          // feature-half [wj*64, +64)
    const int pbase = blockIdx.x * PTS;
    const int p = t >> 1, h = t & 1;    // 2 threads per point (nv ownership)

    // ---------------- init ----------------
    if (t < 128) {
        tw2_sh[t] = tw2[t];
        xaug[t * AS + 8] = (f16)1.0f;          // bias lane
        #pragma unroll
        for (int c = 9; c < 16; ++c) xaug[t * AS + c] = (f16)0.0f;
    }
    const float tb2_0 = tb2[0];

    // nv gather: feat 16h+j = plane j*4+2h; coalesced scalar loads.
    f16x8 nva, nvb;
    {
        const int P = pbase + p;
        #pragma unroll
        for (int j = 0; j < 8; ++j) {
            nva[j] = nv_ws[(size_t)(j * 4 + 2 * h)     * Ntot + P];
            nvb[j] = nv_ws[(size_t)(j * 4 + 2 * h + 1) * Ntot + P];
        }
    }
    if (h == 0) *(f16x8*)&xaug[p * AS] = nva;   // layer-0 feats 0..7

    // prologue: stage L0's Waug (Wm[0] unused — L0 main folded into c0 bias)
    *(f16x8*)&Waug[t * 8] = *(const f16x8*)&waugf[t * 8];
    __syncthreads();   // init + L0 aug rows + L0 Waug visible to all waves

    // ---------------- 5 MFMA layers (L0 = aug-only) ----------------
    const f32x4 z4 = {0.f, 0.f, 0.f, 0.f};
    f32x4 acc[4][4];                    // [pt-group][mt-local]
    f16x8 wreg[8], areg;                // T14: next-layer weights in flight
    #pragma unroll 1
    for (int L = 0; L < 5; ++L) {
        if (L < 4) {   // issue L+1 weight loads NOW; latency hides under compute
            const f16* wsrc = wf + (L + 1) * 16384;
            #pragma unroll
            for (int i = 0; i < 8; ++i)
                wreg[i] = *(const f16x8*)&wsrc[(t + i * 256) * 8];
            areg = *(const f16x8*)&waugf[(size_t)(L + 1) * 2048 + t * 8];
        }

        if (L == 0) {   // only L0 needs explicit zero (aug accumulates into it)
            #pragma unroll
            for (int pg = 0; pg < 4; ++pg)
                #pragma unroll
                for (int mtl = 0; mtl < 4; ++mtl) acc[pg][mtl] = z4;
        }
        __builtin_amdgcn_s_setprio(1);   // T5: favor compute-phase waves
        if (L) {
            #pragma unroll
            for (int c = 0; c < 4; ++c) {   // main K=128
                const int kc = c * 32 + q * 8;
                f16x8 xb[4];
                #pragma unroll
                for (int pg = 0; pg < 4; ++pg)
                    xb[pg] = *(const f16x8*)&xa[(wi * 64 + pg * 16 + l15) * XS + kc];
                #pragma unroll
                for (int mtl = 0; mtl < 4; ++mtl) {
                    const f16x8 aw = *(const f16x8*)
                        &Wm[(((wj * 4 + mtl) * 4 + c) * 64 + lane) * 8]; // lane-linear
                    #pragma unroll
                    for (int pg = 0; pg < 4; ++pg) {
                        const f32x4 ci = (c == 0) ? z4 : acc[pg][mtl];  // compile-time
                        acc[pg][mtl] = __builtin_amdgcn_mfma_f32_16x16x32_f16(aw, xb[pg], ci, 0, 0, 0);
                    }
                }
            }
        }
        {   // aug chunk: K=16 MFMA (covers nv8+bias exactly); all lanes active
            f16x4 xb4[4];
            #pragma unroll
            for (int pg = 0; pg < 4; ++pg)
                xb4[pg] = *(const f16x4*)&xaug[(wi * 64 + pg * 16 + l15) * AS + q * 4];
            #pragma unroll
            for (int mtl = 0; mtl < 4; ++mtl) {
                const f16x4 awa = *(const f16x4*)&Waug[((wj * 4 + mtl) * 64 + lane) * 4];
                #pragma unroll
                for (int pg = 0; pg < 4; ++pg)
                    acc[pg][mtl] = __builtin_amdgcn_mfma_f32_16x16x16f16(
                        awa, xb4[pg], acc[pg][mtl], 0, 0, 0);
            }
        }
        __builtin_amdgcn_s_setprio(0);

        if (L < 4) {
            // epilogue COMPUTE stays here (overlaps sibling MFMA tails):
            // lrelu + f16-pack into registers; no LDS writes yet.
            f16x4 hv[4][4];
            #pragma unroll
            for (int pg = 0; pg < 4; ++pg)
                #pragma unroll
                for (int mtl = 0; mtl < 4; ++mtl)
                    #pragma unroll
                    for (int r = 0; r < 4; ++r) {
                        float v = acc[pg][mtl][r];
                        v = fmaxf(v, 0.01f * v);
                        hv[pg][mtl][r] = (f16)v;
                    }
            __syncthreads();   // ALL reads of xa/xaug/Wm/Waug for layer L done
            // now the writes (race-safe): activations + nv + staged weights
            #pragma unroll
            for (int pg = 0; pg < 4; ++pg) {
                const int pr = (wi * 64 + pg * 16 + l15) * XS;
                #pragma unroll
                for (int mtl = 0; mtl < 4; ++mtl)
                    *(f16x4*)&xa[pr + wj * 64 + mtl * 16 + q * 4] = hv[pg][mtl];
            }
            if (L < 3) {   // next layer's nv into xaug (owning thread)
                const int Ln = L + 1;
                if ((Ln >> 1) == h)
                    *(f16x8*)&xaug[p * AS] = (Ln & 1) ? nvb : nva;
            }
            {   // write the prefetched L+1 weights (loads long since landed)
                #pragma unroll
                for (int i = 0; i < 8; ++i)
                    *(f16x8*)&Wm[(t + i * 256) * 8] = wreg[i];
                *(f16x8*)&Waug[t * 8] = areg;
            }
            __syncthreads();   // writes visible before next layer's reads
        } else {
            // head: partial dot over this wave's 64 features; combine via pp
            #pragma unroll
            for (int pg = 0; pg < 4; ++pg) {
                float s = 0.f;
                #pragma unroll
                for (int mtl = 0; mtl < 4; ++mtl) {
                    const f32x4 w4 = *(const f32x4*)&tw2_sh[wj * 64 + mtl * 16 + q * 4];
                    #pragma unroll
                    for (int r = 0; r < 4; ++r) {
                        float v = acc[pg][mtl][r];
                        v = fmaxf(v, 0.01f * v);
                        s += w4[r] * v;
                    }
                }
                s += __shfl_xor(s, 16);
                s += __shfl_xor(s, 32);
                if (q == 0) pp[wj][wi * 64 + pg * 16 + l15] = s;
            }
            __syncthreads();
            if (t < 128)
                out[pbase + t] = pp[0][t] + pp[1][t] + tb2_0;
        }
    }
}

extern "C" void kernel_launch(void* const* d_in, const int* in_sizes, int n_in,
                              void* d_out, int out_size, void* d_ws, size_t ws_size,
                              hipStream_t stream) {
    const float* noise  = (const float*)d_in[0];
    const float* coords = (const float*)d_in[1];
    const float* trans  = (const float*)d_in[2];
    const float* ivec   = (const float*)d_in[3];
    const float* lw     = (const float*)d_in[4];
    const float* lb     = (const float*)d_in[5];
    const float* lnw    = (const float*)d_in[6];
    const float* tw1    = (const float*)d_in[7];
    const float* tb1    = (const float*)d_in[8];
    const float* tw2    = (const float*)d_in[9];
    const float* tb2    = (const float*)d_in[10];
    float* o            = (float*)d_out;

    const int N = in_sizes[1] / 2;                    // coords is [N,2]
    // ws layout: nv [32 planes][N] f16 (16 MiB) | wf | waug (K16) | quads
    f16* nv    = (f16*)d_ws;
    const size_t NV = (size_t)N * 32;                 // f16 units
    f16* wfp   = nv + NV;
    f16* waugp = wfp + 5 * 16384;
    f16* qn    = waugp + 5 * 2048;                    // waug: 2560 frags x 4 f16
    const size_t need_full = (NV + 5 * 16384 + 5 * 2048
                              + (size_t)32 * 256 * 256 * 4) * sizeof(f16);

    if (ws_size >= need_full) {   // ws_size constant across calls -> graph-safe
        pack_all_k<<<1024 + 50, 256, 0, stream>>>(noise, qn, lw, lnw, lb, tw1, tb1,
                                                  ivec, wfp, waugp);
        sample_kernel<true><<<(N / 2048) * 8, 256, 0, stream>>>(qn, coords, trans, nv, N);
    } else {
        pack_w_k<<<50, 256, 0, stream>>>(lw, lnw, lb, tw1, tb1, ivec, wfp, waugp);
        sample_kernel<false><<<(N / 2048) * 8, 256, 0, stream>>>(noise, coords, trans, nv, N);
    }
    mlp_kernel<<<N / PTS, 256, 0, stream>>>(nv, wfp, waugp, tw2, tb2, o, N);
}

// Round 16
// 203.432 us; speedup vs baseline: 1.0258x; 1.0258x over previous
//
#include <hip/hip_runtime.h>

typedef _Float16 f16;
typedef f16 f16x4 __attribute__((ext_vector_type(4)));
typedef f16 f16x8 __attribute__((ext_vector_type(8)));
typedef float f32x4 __attribute__((ext_vector_type(4)));

#define RES 512
#define PTS 128     // mlp: points per block
#define XS  136     // f16 stride: 272B row, 16B-aligned, b128 phase-minimal
#define AS  20      // 40B row: aug xb4 banks (10*l15)%32 all-distinct -> conflict-free

// R26: recombination of the two best measured halves. R25 was a split: mlp
// AS=20 worked (66.0->63.0us, conflicts 6.2M->4.5M as predicted) but the
// bundled sample changes (ILP 4->8 + tile64) regressed ~5us -> total 208.7.
// This round: R24's sample+pack verbatim (ILP=4, 2x16 quad layout — inside
// the 206.5 total) + R25's mlp verbatim (AS=20, K=16 aug, setprio — measured
// 63.0). Pure recombination, no new mechanisms; waug K16 format shared.
// Next round can A/B sample-ILP8 alone against this baseline if it holds.

// ---------------------------------------------------------------- pack kernels
__device__ __forceinline__
void pack_w_body(int g, const float* __restrict__ lw, const float* __restrict__ lnw,
                 const float* __restrict__ lb, const float* __restrict__ tw1,
                 const float* __restrict__ tb1, const float* __restrict__ ivec,
                 f16* __restrict__ wf, f16* __restrict__ waugf) {
    if (g < 10240) {            // Wm fragments: 5 layers x 32 frags x 64 lanes
        const int L = g >> 11, r = g & 2047;
        const int lane = r & 63, frag = r >> 6;
        const int q = lane >> 4, l15 = lane & 15;
        const int mt = frag >> 2, c = frag & 3;
        const float* src = ((L < 4) ? (lw + L * 16384) : tw1)
                           + (mt * 16 + l15) * 128 + c * 32 + q * 8;
        f16x8 h;
        #pragma unroll
        for (int j = 0; j < 8; ++j) h[j] = (f16)src[j];
        *(f16x8*)(wf + (size_t)g * 8) = h;
    } else {                    // Waug K=16 frags: 5 layers x 8 frags x 64 lanes
        const int ga = g - 10240;            // < 2560
        const int L = ga >> 9, r = ga & 511;
        const int lane = r & 63, mt = r >> 6;
        const int q = lane >> 4, l15 = lane & 15;
        const int row = mt * 16 + l15;
        f16x4 h = {};
        if (L < 4 && q < 2) {                // k=q*4+j in 0..7: lnw slice
            const float* src = lnw + L * 1024 + row * 8 + q * 4;
            #pragma unroll
            for (int j = 0; j < 4; ++j) h[j] = (f16)src[j];
        }
        if (q == 2) {                        // k=8: bias (L0: + lw0@ivec const)
            if (L == 0) {
                float s = lb[row];
                const float4* w4 = (const float4*)(lw + row * 128);
                const float4* v4 = (const float4*)ivec;
                #pragma unroll 8
                for (int k = 0; k < 32; ++k) {
                    const float4 w = w4[k], v = v4[k];
                    s += w.x * v.x + w.y * v.y + w.z * v.z + w.w * v.w;
                }
                h[0] = (f16)s;
            } else {
                h[0] = (f16)((L < 4) ? lb[L * 128 + row] : tb1[row]);
            }
        }
        *(f16x4*)(waugf + (size_t)ga * 4) = h;
    }
}

__global__ __launch_bounds__(256)
void pack_all_k(const float* __restrict__ n, f16* __restrict__ q,
                const float* __restrict__ lw,  const float* __restrict__ lnw,
                const float* __restrict__ lb,  const float* __restrict__ tw1,
                const float* __restrict__ tb1, const float* __restrict__ ivec,
                f16* __restrict__ wf, f16* __restrict__ waugf) {
    const int b = blockIdx.x;
    if (b < 8192) {   // quad packing: one thread per 2x2 texel quad
        const int idx = b * 256 + threadIdx.x;
        const int qx = idx & 255, rest = idx >> 8;
        const int qy = rest & 255, m = rest >> 8;
        const float* src = n + ((size_t)m * 512 + 2 * qy) * 512 + 2 * qx;
        const float2 r0 = *(const float2*)(src);
        const float2 r1 = *(const float2*)(src + 512);
        f16x4 o; o[0]=(f16)r0.x; o[1]=(f16)r0.y; o[2]=(f16)r1.x; o[3]=(f16)r1.y;
        *(f16x4*)(q + (size_t)idx * 4) = o;
    } else {
        pack_w_body((b - 8192) * 256 + threadIdx.x, lw, lnw, lb, tw1, tb1, ivec, wf, waugf);
    }
}

__global__ __launch_bounds__(256)
void pack_w_k(const float* __restrict__ lw,  const float* __restrict__ lnw,
              const float* __restrict__ lb,  const float* __restrict__ tw1,
              const float* __restrict__ tb1, const float* __restrict__ ivec,
              f16* __restrict__ wf, f16* __restrict__ waugf) {
    pack_w_body(blockIdx.x * 256 + threadIdx.x, lw, lnw, lb, tw1, tb1, ivec, wf, waugf);
}

// ---------------------------------------------------------------- sample kernel
__device__ __forceinline__ float quad_tap(uint2 q, int sy, int sx) {
    unsigned w = sy ? q.y : q.x;          // row select within quad
    w >>= (sx << 4);                      // col select (low/high half)
    union { unsigned short u; f16 h; } cv; cv.u = (unsigned short)w;
    return (float)cv.h;
}

template <bool QUAD>
__global__ __launch_bounds__(256, 4)
void sample_kernel(const void* __restrict__ noise_v,
                   const float* __restrict__ coords,
                   const float* __restrict__ trans,
                   f16* __restrict__ nv_ws, const int Ntot)
{
    __shared__ float T_sh[128];
    const int t = threadIdx.x;
    if (t < 128) T_sh[t] = trans[t];
    __syncthreads();

    const int g = blockIdx.x & 7;                     // feature group -> XCD pin
    const int pb = (blockIdx.x >> 3) * 1024 + t;      // 4 points: pb + 256*j

    // cost-balanced plane sets (expensive planes m=9..31 split 3/..3/2)
    int mk[4];
    if (g < 7) { mk[0] = g; mk[1] = g + 9; mk[2] = g + 17; mk[3] = g + 25; }
    else       { mk[0] = 7; mk[1] = 8;     mk[2] = 16;     mk[3] = 24;     }

    float2 c[4];
    #pragma unroll
    for (int j = 0; j < 4; ++j)
        c[j] = *(const float2*)(coords + (pb + 256 * j) * 2);

    float nvr[4][4];
    {
        #pragma clang fp contract(off)
        #pragma unroll
        for (int j = 0; j < 4; ++j) {
            const float cx = c[j].x;
            const float cy = c[j].y;
            #pragma unroll
            for (int k = 0; k < 4; ++k) {
                const int m = mk[k];
                const float T00 = T_sh[m*4+0], T01 = T_sh[m*4+1];
                const float T10 = T_sh[m*4+2], T11 = T_sh[m*4+3];
                const float p0x = T00 * cx;                       // k=0: fl(cx*T00)
                const float p0y = T10 * cx;
                const float ncx = __builtin_fmaf(T01, cy, p0x);   // k=1: fused accumulate
                const float ncy = __builtin_fmaf(T11, cy, p0y);
                const float u = ncx - 0.5f;
                const float v = ncy - 0.5f;
                const float xf = floorf(u), yf = floorf(v);
                const float xw = u - xf, yw = v - yf;
                int ix = (xf >= 2147483648.0f || xf < -2147483648.0f) ? (int)(-2147483647 - 1) : (int)xf;
                int iy = (yf >= 2147483648.0f || yf < -2147483648.0f) ? (int)(-2147483647 - 1) : (int)yf;
                const int x0 = ix & (RES - 1);
                const int x1 = (int)(((unsigned)ix + 1u) & (unsigned)(RES - 1));
                const int y0 = iy & (RES - 1);
                const int y1 = (int)(((unsigned)iy + 1u) & (unsigned)(RES - 1));
                float i00, i01, i10, i11;
                if constexpr (QUAD) {
                    const f16* pl = (const f16*)noise_v + (size_t)m * (256 * 256 * 4);
                    const int qx0 = x0 >> 1, sx0 = x0 & 1;
                    const int qx1 = x1 >> 1, sx1 = x1 & 1;
                    const int qy0 = y0 >> 1, sy0 = y0 & 1;
                    const int qy1 = y1 >> 1, sy1 = y1 & 1;
                    const uint2 qa = *(const uint2*)(pl + (qy0 * 256 + qx0) * 4);
                    const uint2 qb = *(const uint2*)(pl + (qy0 * 256 + qx1) * 4);
                    const uint2 qc = *(const uint2*)(pl + (qy1 * 256 + qx0) * 4);
                    const uint2 qd = *(const uint2*)(pl + (qy1 * 256 + qx1) * 4);
                    i00 = quad_tap(qa, sy0, sx0);
                    i01 = quad_tap(qb, sy0, sx1);
                    i10 = quad_tap(qc, sy1, sx0);
                    i11 = quad_tap(qd, sy1, sx1);
                } else {
                    const float* pl = (const float*)noise_v + (size_t)m * (RES * RES);
                    i00 = pl[y0 * RES + x0];
                    i01 = pl[y0 * RES + x1];
                    i10 = pl[y1 * RES + x0];
                    i11 = pl[y1 * RES + x1];
                }
                const float a0 = i00 + (i01 - i00) * xw;
                const float a1 = i10 + (i11 - i10) * xw;
                nvr[j][k] = a0 + (a1 - a0) * yw;
            }
        }
    }
    #pragma unroll
    for (int j = 0; j < 4; ++j) {
        #pragma unroll
        for (int k = 0; k < 4; ++k) {          // nv slot(m) = (m&7)*4 + (m>>3)
            const int m = mk[k];
            const int slot = (m & 7) * 4 + (m >> 3);
            nv_ws[(size_t)slot * Ntot + pb + 256 * j] = (f16)nvr[j][k];
        }
    }
}

// ---------------------------------------------------------------- mlp kernel
__global__ __launch_bounds__(256, 2)
void mlp_kernel(const f16* __restrict__ nv_ws,
                const f16* __restrict__ wf,
                const f16* __restrict__ waugf,
                const float* __restrict__ tw2,
                const float* __restrict__ tb2,
                float* __restrict__ out, const int Ntot)
{
    __shared__ f16 Wm[16384];           // 32 frags x 512 f16 = 32768 B, lane-linear
    __shared__ f16 Waug[2048];          //  8 K16-frags x 256 f16 = 4096 B
    __shared__ f16 xa[PTS * XS];        // 34816 B
    __shared__ f16 xaug[PTS * AS];      //  5120 B (40B rows, conflict-free xb4)
    __shared__ __align__(16) float tw2_sh[128];   // 512 B
    __shared__ float pp[2][PTS];        // 1024 B; total 78336 B

    const int t    = threadIdx.x;
    const int wave = t >> 6;
    const int lane = t & 63;
    const int q    = lane >> 4;
    const int l15  = lane & 15;
    const int wi   = wave >> 1;         // point-half  [wi*64, +64)
    const int wj   = wave & 1;          // feature-half [wj*64, +64)
    const int pbase = blockIdx.x * PTS;
    const int p = t >> 1, h = t & 1;    // 2 threads per point (nv ownership)

    // ---------------- init ----------------
    if (t < 128) {
        tw2_sh[t] = tw2[t];
        xaug[t * AS + 8] = (f16)1.0f;          // bias lane
        #pragma unroll
        for (int c = 9; c < 16; ++c) xaug[t * AS + c] = (f16)0.0f;
    }
    const float tb2_0 = tb2[0];

    // nv gather: feat 16h+j = plane j*4+2h; coalesced scalar loads.
    f16x8 nva, nvb;
    {
        const int P = pbase + p;
        #pragma unroll
        for (int j = 0; j < 8; ++j) {
            nva[j] = nv_ws[(size_t)(j * 4 + 2 * h)     * Ntot + P];
            nvb[j] = nv_ws[(size_t)(j * 4 + 2 * h + 1) * Ntot + P];
        }
    }
    if (h == 0) *(f16x8*)&xaug[p * AS] = nva;   // layer-0 feats 0..7

    // prologue: stage L0's Waug (Wm[0] unused — L0 main folded into c0 bias)
    *(f16x8*)&Waug[t * 8] = *(const f16x8*)&waugf[t * 8];
    __syncthreads();   // init + L0 aug rows + L0 Waug visible to all waves

    // ---------------- 5 MFMA layers (L0 = aug-only) ----------------
    const f32x4 z4 = {0.f, 0.f, 0.f, 0.f};
    f32x4 acc[4][4];                    // [pt-group][mt-local]
    f16x8 wreg[8], areg;                // T14: next-layer weights in flight
    #pragma unroll 1
    for (int L = 0; L < 5; ++L) {
        if (L < 4) {   // issue L+1 weight loads NOW; latency hides under compute
            const f16* wsrc = wf + (L + 1) * 16384;
            #pragma unroll
            for (int i = 0; i < 8; ++i)
                wreg[i] = *(const f16x8*)&wsrc[(t + i * 256) * 8];
            areg = *(const f16x8*)&waugf[(size_t)(L + 1) * 2048 + t * 8];
        }

        if (L == 0) {   // only L0 needs explicit zero (aug accumulates into it)
            #pragma unroll
            for (int pg = 0; pg < 4; ++pg)
                #pragma unroll
                for (int mtl = 0; mtl < 4; ++mtl) acc[pg][mtl] = z4;
        }
        __builtin_amdgcn_s_setprio(1);   // T5: favor compute-phase waves
        if (L) {
            #pragma unroll
            for (int c = 0; c < 4; ++c) {   // main K=128
                const int kc = c * 32 + q * 8;
                f16x8 xb[4];
                #pragma unroll
                for (int pg = 0; pg < 4; ++pg)
                    xb[pg] = *(const f16x8*)&xa[(wi * 64 + pg * 16 + l15) * XS + kc];
                #pragma unroll
                for (int mtl = 0; mtl < 4; ++mtl) {
                    const f16x8 aw = *(const f16x8*)
                        &Wm[(((wj * 4 + mtl) * 4 + c) * 64 + lane) * 8]; // lane-linear
                    #pragma unroll
                    for (int pg = 0; pg < 4; ++pg) {
                        const f32x4 ci = (c == 0) ? z4 : acc[pg][mtl];  // compile-time
                        acc[pg][mtl] = __builtin_amdgcn_mfma_f32_16x16x32_f16(aw, xb[pg], ci, 0, 0, 0);
                    }
                }
            }
        }
        {   // aug chunk: K=16 MFMA (covers nv8+bias exactly); all lanes active
            f16x4 xb4[4];
            #pragma unroll
            for (int pg = 0; pg < 4; ++pg)
                xb4[pg] = *(const f16x4*)&xaug[(wi * 64 + pg * 16 + l15) * AS + q * 4];
            #pragma unroll
            for (int mtl = 0; mtl < 4; ++mtl) {
                const f16x4 awa = *(const f16x4*)&Waug[((wj * 4 + mtl) * 64 + lane) * 4];
                #pragma unroll
                for (int pg = 0; pg < 4; ++pg)
                    acc[pg][mtl] = __builtin_amdgcn_mfma_f32_16x16x16f16(
                        awa, xb4[pg], acc[pg][mtl], 0, 0, 0);
            }
        }
        __builtin_amdgcn_s_setprio(0);

        if (L < 4) {
            // epilogue COMPUTE stays here (overlaps sibling MFMA tails):
            // lrelu + f16-pack into registers; no LDS writes yet.
            f16x4 hv[4][4];
            #pragma unroll
            for (int pg = 0; pg < 4; ++pg)
                #pragma unroll
                for (int mtl = 0; mtl < 4; ++mtl)
                    #pragma unroll
                    for (int r = 0; r < 4; ++r) {
                        float v = acc[pg][mtl][r];
                        v = fmaxf(v, 0.01f * v);
                        hv[pg][mtl][r] = (f16)v;
                    }
            __syncthreads();   // ALL reads of xa/xaug/Wm/Waug for layer L done
            // now the writes (race-safe): activations + nv + staged weights
            #pragma unroll
            for (int pg = 0; pg < 4; ++pg) {
                const int pr = (wi * 64 + pg * 16 + l15) * XS;
                #pragma unroll
                for (int mtl = 0; mtl < 4; ++mtl)
                    *(f16x4*)&xa[pr + wj * 64 + mtl * 16 + q * 4] = hv[pg][mtl];
            }
            if (L < 3) {   // next layer's nv into xaug (owning thread)
                const int Ln = L + 1;
                if ((Ln >> 1) == h)
                    *(f16x8*)&xaug[p * AS] = (Ln & 1) ? nvb : nva;
            }
            {   // write the prefetched L+1 weights (loads long since landed)
                #pragma unroll
                for (int i = 0; i < 8; ++i)
                    *(f16x8*)&Wm[(t + i * 256) * 8] = wreg[i];
                *(f16x8*)&Waug[t * 8] = areg;
            }
            __syncthreads();   // writes visible before next layer's reads
        } else {
            // head: partial dot over this wave's 64 features; combine via pp
            #pragma unroll
            for (int pg = 0; pg < 4; ++pg) {
                float s = 0.f;
                #pragma unroll
                for (int mtl = 0; mtl < 4; ++mtl) {
                    const f32x4 w4 = *(const f32x4*)&tw2_sh[wj * 64 + mtl * 16 + q * 4];
                    #pragma unroll
                    for (int r = 0; r < 4; ++r) {
                        float v = acc[pg][mtl][r];
                        v = fmaxf(v, 0.01f * v);
                        s += w4[r] * v;
                    }
                }
                s += __shfl_xor(s, 16);
                s += __shfl_xor(s, 32);
                if (q == 0) pp[wj][wi * 64 + pg * 16 + l15] = s;
            }
            __syncthreads();
            if (t < 128)
                out[pbase + t] = pp[0][t] + pp[1][t] + tb2_0;
        }
    }
}

extern "C" void kernel_launch(void* const* d_in, const int* in_sizes, int n_in,
                              void* d_out, int out_size, void* d_ws, size_t ws_size,
                              hipStream_t stream) {
    const float* noise  = (const float*)d_in[0];
    const float* coords = (const float*)d_in[1];
    const float* trans  = (const float*)d_in[2];
    const float* ivec   = (const float*)d_in[3];
    const float* lw     = (const float*)d_in[4];
    const float* lb     = (const float*)d_in[5];
    const float* lnw    = (const float*)d_in[6];
    const float* tw1    = (const float*)d_in[7];
    const float* tb1    = (const float*)d_in[8];
    const float* tw2    = (const float*)d_in[9];
    const float* tb2    = (const float*)d_in[10];
    float* o            = (float*)d_out;

    const int N = in_sizes[1] / 2;                    // coords is [N,2]
    // ws layout: nv [32 planes][N] f16 (16 MiB) | wf | waug (K16) | quads
    f16* nv    = (f16*)d_ws;
    const size_t NV = (size_t)N * 32;                 // f16 units
    f16* wfp   = nv + NV;
    f16* waugp = wfp + 5 * 16384;
    f16* qn    = waugp + 5 * 2048;                    // waug: 2560 frags x 4 f16
    const size_t need_full = (NV + 5 * 16384 + 5 * 2048
                              + (size_t)32 * 256 * 256 * 4) * sizeof(f16);

    if (ws_size >= need_full) {   // ws_size constant across calls -> graph-safe
        pack_all_k<<<8192 + 50, 256, 0, stream>>>(noise, qn, lw, lnw, lb, tw1, tb1,
                                                  ivec, wfp, waugp);
        sample_kernel<true><<<(N / 1024) * 8, 256, 0, stream>>>(qn, coords, trans, nv, N);
    } else {
        pack_w_k<<<50, 256, 0, stream>>>(lw, lnw, lb, tw1, tb1, ivec, wfp, waugp);
        sample_kernel<false><<<(N / 1024) * 8, 256, 0, stream>>>(noise, coords, trans, nv, N);
    }
    mlp_kernel<<<N / PTS, 256, 0, stream>>>(nv, wfp, waugp, tw2, tb2, o, N);
}